// Round 1
// baseline (175.828 us; speedup 1.0000x reference)
//
#include <hip/hip_runtime.h>
#include <hip/hip_bf16.h>

// Problem constants
#define BB   128   // batch
#define SS   37    // sensors
#define TT   2048  // time steps
#define DD   256   // d_model
#define STT  8     // static features
#define CC   2     // classes
#define MER  264   // DD + STT
#define FF   74    // 2*SS features

#define NC    8            // t-chunks per batch row
#define CHUNK (TT / NC)    // 256
#define RW    76           // per-b reduction row: 74 feature sums + smask + stime
#define NSW   10           // sensors per wave (4 waves cover 40 >= 37)

// ---------------------------------------------------------------------------
// Kernel 1: streaming reduction over T.
// For each b: red[b][f]   = sum_t x_time[b,t,f]        (f = 0..73)
//             red[b][74]  = sum_t mask[b,t]
//             red[b][75]  = sum_t mask[b,t]*time[b,t]
// mask[b,t] = any feature nonzero. Since mask==0 implies all features zero,
// the feature sums need no masking (mask*x_time == x_time).
// ---------------------------------------------------------------------------
__global__ __launch_bounds__(256) void reduce_kernel(
    const float* __restrict__ x,      // [B,S,T]
    const int*   __restrict__ smk,    // [B,S,T]
    const float* __restrict__ tarr,   // [B,T]
    float* __restrict__ red)          // [B,RW] accumulators (pre-zeroed)
{
    const int blk   = blockIdx.x;      // 0 .. B*NC-1
    const int b     = blk / NC;
    const int chunk = blk % NC;
    const int t0    = chunk * CHUNK;
    const int wave  = threadIdx.x >> 6;
    const int lane  = threadIdx.x & 63;
    const int sbase = wave * NSW;

    float accx[NSW];
    float accm[NSW];
#pragma unroll
    for (int i = 0; i < NSW; ++i) { accx[i] = 0.f; accm[i] = 0.f; }

    __shared__ unsigned char nzf[4][CHUNK];   // per-wave nonzero flags per t

    for (int j = 0; j < CHUNK; j += 64) {
        const int t = t0 + j + lane;
        unsigned nz = 0;
#pragma unroll
        for (int i = 0; i < NSW; ++i) {
            const int s = sbase + i;
            if (s < SS) {   // wave-uniform branch
                const size_t idx = ((size_t)b * SS + s) * TT + t;
                const float xv = x[idx];
                const int   mv = smk[idx];
                accx[i] += xv;
                accm[i] += (float)mv;
                nz |= (unsigned)((xv != 0.0f) | (mv != 0));
            }
        }
        nzf[wave][j + lane] = (unsigned char)nz;
    }
    __syncthreads();

    // combine nonzero flags across waves; accumulate smask / stime partials
    float cnt = 0.f, tsum = 0.f;
    for (int tt = threadIdx.x; tt < CHUNK; tt += 256) {
        const unsigned m = (unsigned)nzf[0][tt] | nzf[1][tt] | nzf[2][tt] | nzf[3][tt];
        if (m) { cnt += 1.f; tsum += tarr[(size_t)b * TT + t0 + tt]; }
    }
    for (int off = 32; off; off >>= 1) {
        cnt  += __shfl_down(cnt,  off, 64);
        tsum += __shfl_down(tsum, off, 64);
    }
    __shared__ float rbuf[8];
    if (lane == 0) { rbuf[wave] = cnt; rbuf[4 + wave] = tsum; }
    __syncthreads();
    if (threadIdx.x == 0) {
        atomicAdd(&red[b * RW + 74], rbuf[0] + rbuf[1] + rbuf[2] + rbuf[3]);
        atomicAdd(&red[b * RW + 75], rbuf[4] + rbuf[5] + rbuf[6] + rbuf[7]);
    }

    // per-sensor sums: wave-level shuffle reduction, then one atomic per value
#pragma unroll
    for (int i = 0; i < NSW; ++i) {
        const int s = sbase + i;
        if (s < SS) {
            float vx = accx[i], vm = accm[i];
            for (int off = 32; off; off >>= 1) {
                vx += __shfl_down(vx, off, 64);
                vm += __shfl_down(vm, off, 64);
            }
            if (lane == 0) {
                atomicAdd(&red[b * RW + s],      vx);
                atomicAdd(&red[b * RW + SS + s], vm);
            }
        }
    }
}

// ---------------------------------------------------------------------------
// Kernel 2: per-batch head. One block per b.
// pooled = (sxt @ W_sensor + smask*(b_sensor+b_time) + stime*W_time) / denom
// comb   = relu([pooled, static@W_static+b_static] @ W_merge + b_merge)
// out    = comb @ W_cls + b_cls
// ---------------------------------------------------------------------------
__global__ __launch_bounds__(256) void head_kernel(
    const float* __restrict__ red,       // [B,RW]
    const float* __restrict__ statics,   // [B,ST]
    const float* __restrict__ W_sensor,  // [74,256]
    const float* __restrict__ b_sensor,  // [256]
    const float* __restrict__ W_time,    // [1,256]
    const float* __restrict__ b_time,    // [256]
    const float* __restrict__ W_static,  // [8,8]
    const float* __restrict__ b_static,  // [8]
    const float* __restrict__ W_merge,   // [264,264]
    const float* __restrict__ b_merge,   // [264]
    const float* __restrict__ W_cls,     // [264,2]
    const float* __restrict__ b_cls,     // [2]
    float* __restrict__ out)             // [B,2]
{
    const int b   = blockIdx.x;
    const int tid = threadIdx.x;

    __shared__ float sred[RW];
    __shared__ float comb[MER];
    __shared__ float comb2[MER];

    if (tid < RW) sred[tid] = red[b * RW + tid];
    __syncthreads();

    const float smask = sred[74];
    const float stime = sred[75];
    const float inv   = 1.0f / fmaxf(smask, 1e-9f);

    // pooled: 256 threads, one output dim each
    {
        const int d = tid;
        float acc = smask * (b_sensor[d] + b_time[d]) + stime * W_time[d];
#pragma unroll 2
        for (int f = 0; f < FF; ++f)
            acc += sred[f] * W_sensor[f * DD + d];
        comb[d] = acc * inv;
    }
    if (tid < STT) {
        float acc = b_static[tid];
#pragma unroll
        for (int i = 0; i < STT; ++i)
            acc += statics[b * STT + i] * W_static[i * STT + tid];
        comb[DD + tid] = acc;
    }
    __syncthreads();

    // merge layer: 264 outputs over 256 threads
    for (int j = tid; j < MER; j += 256) {
        float acc = b_merge[j];
        for (int i = 0; i < MER; ++i)
            acc += comb[i] * W_merge[i * MER + j];
        comb2[j] = fmaxf(acc, 0.f);
    }
    __syncthreads();

    // classifier: 2 outputs
    if (tid < CC) {
        float acc = b_cls[tid];
        for (int i = 0; i < MER; ++i)
            acc += comb2[i] * W_cls[i * CC + tid];
        out[b * CC + tid] = acc;
    }
}

extern "C" void kernel_launch(void* const* d_in, const int* in_sizes, int n_in,
                              void* d_out, int out_size, void* d_ws, size_t ws_size,
                              hipStream_t stream) {
    const float* x        = (const float*)d_in[0];
    const float* statics  = (const float*)d_in[1];
    const float* tarr     = (const float*)d_in[2];
    const int*   smk      = (const int*)  d_in[3];
    const float* W_sensor = (const float*)d_in[4];
    const float* b_sensor = (const float*)d_in[5];
    const float* W_time   = (const float*)d_in[6];
    const float* b_time   = (const float*)d_in[7];
    const float* W_static = (const float*)d_in[8];
    const float* b_static = (const float*)d_in[9];
    const float* W_merge  = (const float*)d_in[10];
    const float* b_merge  = (const float*)d_in[11];
    const float* W_cls    = (const float*)d_in[12];
    const float* b_cls    = (const float*)d_in[13];
    float* out = (float*)d_out;
    float* red = (float*)d_ws;   // B*RW floats

    // ws is poisoned with 0xAA before every timed call — zero the accumulators
    hipMemsetAsync(red, 0, (size_t)BB * RW * sizeof(float), stream);

    reduce_kernel<<<BB * NC, 256, 0, stream>>>(x, smk, tarr, red);
    head_kernel<<<BB, 256, 0, stream>>>(red, statics, W_sensor, b_sensor,
                                        W_time, b_time, W_static, b_static,
                                        W_merge, b_merge, W_cls, b_cls, out);
}

// Round 2
// 145.742 us; speedup vs baseline: 1.2064x; 1.2064x over previous
//
#include <hip/hip_runtime.h>
#include <hip/hip_bf16.h>

// Problem constants
#define BB   128   // batch
#define SS   37    // sensors
#define TT   2048  // time steps
#define DD   256   // d_model
#define STT  8     // static features
#define CC   2     // classes
#define MER  264   // DD + STT
#define FF   74    // 2*SS features

#define NC    8            // t-chunks per batch row
#define CHUNK (TT / NC)    // 256 = 64 lanes x float4
#define RW    76           // per-b reduction row: 74 feature sums + smask + stime
#define NSW   10           // max sensors per wave (stride-4 interleave covers 37)

// ---------------------------------------------------------------------------
// Kernel 1: streaming reduction over T, float4/int4 vector loads.
// Each block: one (b, 256-t chunk). Each wave covers sensors s = wave + 4*si.
// One float4 + one int4 load per (wave, sensor) covers the whole chunk:
// lane l owns t = t0 + 4l .. 4l+3.
//   red[b][f]  = sum_t x_time[b,t,f]   (f<74; mask*x == x since mask==0 => all 0)
//   red[b][74] = sum_t mask[b,t],  red[b][75] = sum_t mask[b,t]*time[b,t]
// ---------------------------------------------------------------------------
__global__ __launch_bounds__(256) void reduce_kernel(
    const float* __restrict__ x,      // [B,S,T]
    const int*   __restrict__ smk,    // [B,S,T]
    const float* __restrict__ tarr,   // [B,T]
    float* __restrict__ red)          // [B,RW] accumulators (pre-zeroed)
{
    const int blk   = blockIdx.x;      // 0 .. B*NC-1
    const int b     = blk >> 3;
    const int chunk = blk & 7;
    const int t0    = chunk * CHUNK;
    const int wave  = threadIdx.x >> 6;
    const int lane  = threadIdx.x & 63;

    float ax[NSW];   // per-sensor x sums over this lane's 4 t's
    float am[NSW];   // per-sensor mask sums
    unsigned nz = 0; // 4 nonzero flags (bit k = t-slot k), OR over sensors

#pragma unroll
    for (int si = 0; si < NSW; ++si) {
        const int s = wave + 4 * si;
        if (s < SS) {   // wave-uniform
            const size_t base = ((size_t)(b * SS + s)) * TT + t0 + 4 * lane;
            const float4 xv = *(const float4*)(x + base);
            const int4   mv = *(const int4*)(smk + base);
            ax[si] = (xv.x + xv.y) + (xv.z + xv.w);
            am[si] = (float)((mv.x + mv.y) + (mv.z + mv.w));
            nz |= ((xv.x != 0.f) | (mv.x != 0)) ? 1u : 0u;
            nz |= ((xv.y != 0.f) | (mv.y != 0)) ? 2u : 0u;
            nz |= ((xv.z != 0.f) | (mv.z != 0)) ? 4u : 0u;
            nz |= ((xv.w != 0.f) | (mv.w != 0)) ? 8u : 0u;
        } else {
            ax[si] = 0.f; am[si] = 0.f;
        }
    }

    __shared__ unsigned nzp[4][64];
    nzp[wave][lane] = nz;
    __syncthreads();

    // wave 0: combine flags across waves, count + time-sum, reduce, atomics
    if (wave == 0) {
        const unsigned m = nzp[0][lane] | nzp[1][lane] | nzp[2][lane] | nzp[3][lane];
        const float4 tv = *(const float4*)(tarr + (size_t)b * TT + t0 + 4 * lane);
        float cnt = 0.f, tsum = 0.f;
        if (m & 1u) { cnt += 1.f; tsum += tv.x; }
        if (m & 2u) { cnt += 1.f; tsum += tv.y; }
        if (m & 4u) { cnt += 1.f; tsum += tv.z; }
        if (m & 8u) { cnt += 1.f; tsum += tv.w; }
        for (int off = 32; off; off >>= 1) {
            cnt  += __shfl_down(cnt,  off, 64);
            tsum += __shfl_down(tsum, off, 64);
        }
        if (lane == 0) {
            atomicAdd(&red[b * RW + 74], cnt);
            atomicAdd(&red[b * RW + 75], tsum);
        }
    }

    // per-sensor sums: wave shuffle reduction, one atomic per value
#pragma unroll
    for (int si = 0; si < NSW; ++si) {
        const int s = wave + 4 * si;
        if (s < SS) {
            float vx = ax[si], vm = am[si];
            for (int off = 32; off; off >>= 1) {
                vx += __shfl_down(vx, off, 64);
                vm += __shfl_down(vm, off, 64);
            }
            if (lane == 0) {
                atomicAdd(&red[b * RW + s],      vx);
                atomicAdd(&red[b * RW + SS + s], vm);
            }
        }
    }
}

// ---------------------------------------------------------------------------
// Kernel 2: per-batch head, 320 threads (5 waves) per block, one block per b.
// pooled = (sxt @ W_sensor + smask*(b_sensor+b_time) + stime*W_time) / denom
// comb   = relu([pooled, static@W_static+b_static] @ W_merge + b_merge)
// out    = comb @ W_cls + b_cls
// ---------------------------------------------------------------------------
__global__ __launch_bounds__(320) void head_kernel(
    const float* __restrict__ red,       // [B,RW]
    const float* __restrict__ statics,   // [B,ST]
    const float* __restrict__ W_sensor,  // [74,256]
    const float* __restrict__ b_sensor,  // [256]
    const float* __restrict__ W_time,    // [1,256]
    const float* __restrict__ b_time,    // [256]
    const float* __restrict__ W_static,  // [8,8]
    const float* __restrict__ b_static,  // [8]
    const float* __restrict__ W_merge,   // [264,264]
    const float* __restrict__ b_merge,   // [264]
    const float* __restrict__ W_cls,     // [264,2]
    const float* __restrict__ b_cls,     // [2]
    float* __restrict__ out)             // [B,2]
{
    const int b   = blockIdx.x;
    const int tid = threadIdx.x;

    __shared__ float sred[RW];
    __shared__ float comb[MER];
    __shared__ float comb2[MER];
    __shared__ float rbuf[10];

    if (tid < RW) sred[tid] = red[b * RW + tid];
    __syncthreads();

    const float smask = sred[74];
    const float stime = sred[75];
    const float inv   = 1.0f / fmaxf(smask, 1e-9f);

    if (tid < DD) {
        // pooled: one output dim per thread, fully unrolled (74 loads in flight)
        const int d = tid;
        float a0 = smask * (b_sensor[d] + b_time[d]) + stime * W_time[d];
        float a1 = 0.f;
#pragma unroll
        for (int f = 0; f < FF; f += 2) {
            a0 += sred[f]     * W_sensor[f * DD + d];
            a1 += sred[f + 1] * W_sensor[(f + 1) * DD + d];
        }
        comb[d] = (a0 + a1) * inv;
    } else if (tid < DD + STT) {
        const int j = tid - DD;
        float acc = b_static[j];
#pragma unroll
        for (int i = 0; i < STT; ++i)
            acc += statics[b * STT + i] * W_static[i * STT + j];
        comb[DD + j] = acc;
    }
    __syncthreads();

    // merge layer: one output per thread, 8-way unrolled inner loop (8 loads in flight)
    if (tid < MER) {
        const int j = tid;
        float a[8];
#pragma unroll
        for (int k = 0; k < 8; ++k) a[k] = 0.f;
        for (int i = 0; i < MER; i += 8) {   // 264 = 33 * 8
#pragma unroll
            for (int k = 0; k < 8; ++k)
                a[k] += comb[i + k] * W_merge[(i + k) * MER + j];
        }
        const float acc = b_merge[j] +
            ((a[0] + a[1]) + (a[2] + a[3])) + ((a[4] + a[5]) + (a[6] + a[7]));
        comb2[j] = fmaxf(acc, 0.f);
    }
    __syncthreads();

    // classifier: parallel over i, block reduction
    float c0 = 0.f, c1 = 0.f;
    if (tid < MER) {
        const float v = comb2[tid];
        c0 = v * W_cls[tid * CC];
        c1 = v * W_cls[tid * CC + 1];
    }
    for (int off = 32; off; off >>= 1) {
        c0 += __shfl_down(c0, off, 64);
        c1 += __shfl_down(c1, off, 64);
    }
    const int wv = tid >> 6, ln = tid & 63;
    if (ln == 0) { rbuf[wv] = c0; rbuf[5 + wv] = c1; }
    __syncthreads();
    if (tid == 0)
        out[b * CC + 0] = b_cls[0] + rbuf[0] + rbuf[1] + rbuf[2] + rbuf[3] + rbuf[4];
    if (tid == 1)
        out[b * CC + 1] = b_cls[1] + rbuf[5] + rbuf[6] + rbuf[7] + rbuf[8] + rbuf[9];
}

extern "C" void kernel_launch(void* const* d_in, const int* in_sizes, int n_in,
                              void* d_out, int out_size, void* d_ws, size_t ws_size,
                              hipStream_t stream) {
    const float* x        = (const float*)d_in[0];
    const float* statics  = (const float*)d_in[1];
    const float* tarr     = (const float*)d_in[2];
    const int*   smk      = (const int*)  d_in[3];
    const float* W_sensor = (const float*)d_in[4];
    const float* b_sensor = (const float*)d_in[5];
    const float* W_time   = (const float*)d_in[6];
    const float* b_time   = (const float*)d_in[7];
    const float* W_static = (const float*)d_in[8];
    const float* b_static = (const float*)d_in[9];
    const float* W_merge  = (const float*)d_in[10];
    const float* b_merge  = (const float*)d_in[11];
    const float* W_cls    = (const float*)d_in[12];
    const float* b_cls    = (const float*)d_in[13];
    float* out = (float*)d_out;
    float* red = (float*)d_ws;   // B*RW floats

    // ws is poisoned with 0xAA before every timed call — zero the accumulators
    hipMemsetAsync(red, 0, (size_t)BB * RW * sizeof(float), stream);

    reduce_kernel<<<BB * NC, 256, 0, stream>>>(x, smk, tarr, red);
    head_kernel<<<BB, 320, 0, stream>>>(red, statics, W_sensor, b_sensor,
                                        W_time, b_time, W_static, b_static,
                                        W_merge, b_merge, W_cls, b_cls, out);
}

// Round 3
// 145.041 us; speedup vs baseline: 1.2123x; 1.0048x over previous
//
#include <hip/hip_runtime.h>
#include <hip/hip_bf16.h>

// Problem constants
#define BB   128   // batch
#define SS   37    // sensors
#define TT   2048  // time steps
#define DD   256   // d_model
#define STT  8     // static features
#define CC   2     // classes
#define MER  264   // DD + STT
#define FF   74    // 2*SS features

#define NC    4            // t-chunks per batch row
#define CHUNK (TT / NC)    // 512 = 2 x (64 lanes x float4)
#define NJ    (CHUNK / 256)// t-iterations per block (2)
#define RW    76           // partial row: 74 feature sums + cnt + tsum
#define NSW   10           // max sensors per wave (stride-4 interleave covers 37)

// ---------------------------------------------------------------------------
// Kernel 1: streaming reduction over T, float4/int4 vector loads, NO atomics.
// Block (b, chunk) writes its own partial row red[b*NC+chunk][RW]; every slot
// is written by exactly one lane each call, so no zero-init is needed.
//   row[s]     = sum_t x[b,s,t]        (mask*x == x since mask==0 => all 0)
//   row[37+s]  = sum_t smk[b,s,t]
//   row[74]    = sum_t mask[b,t],  row[75] = sum_t mask[b,t]*time[b,t]
// Each wave covers sensors s = wave + 4*si; lane l owns t = tb + 4l..4l+3.
// ---------------------------------------------------------------------------
__global__ __launch_bounds__(256) void reduce_kernel(
    const float* __restrict__ x,      // [B,S,T]
    const int*   __restrict__ smk,    // [B,S,T]
    const float* __restrict__ tarr,   // [B,T]
    float* __restrict__ red)          // [B*NC, RW] partials
{
    const int blk   = blockIdx.x;      // 0 .. B*NC-1
    const int b     = blk >> 2;
    const int chunk = blk & 3;
    const int t0    = chunk * CHUNK;
    const int wave  = threadIdx.x >> 6;
    const int lane  = threadIdx.x & 63;

    float ax[NSW];     // per-sensor x sums over this lane's t's
    float am[NSW];     // per-sensor mask sums
    unsigned nz = 0;   // nonzero flags: bit (4j+k) = t-slot k of iteration j
#pragma unroll
    for (int i = 0; i < NSW; ++i) { ax[i] = 0.f; am[i] = 0.f; }

#pragma unroll
    for (int j = 0; j < NJ; ++j) {
        const int tb = t0 + 256 * j + 4 * lane;
#pragma unroll
        for (int si = 0; si < NSW; ++si) {
            const int s = wave + 4 * si;
            if (s < SS) {   // wave-uniform
                const size_t base = ((size_t)(b * SS + s)) * TT + tb;
                const float4 xv = *(const float4*)(x + base);
                const int4   mv = *(const int4*)(smk + base);
                ax[si] += (xv.x + xv.y) + (xv.z + xv.w);
                am[si] += (float)((mv.x + mv.y) + (mv.z + mv.w));
                unsigned f = (unsigned)((xv.x != 0.f) | (mv.x != 0))
                           | ((unsigned)((xv.y != 0.f) | (mv.y != 0)) << 1)
                           | ((unsigned)((xv.z != 0.f) | (mv.z != 0)) << 2)
                           | ((unsigned)((xv.w != 0.f) | (mv.w != 0)) << 3);
                nz |= f << (4 * j);
            }
        }
    }

    __shared__ unsigned nzp[4][64];
    nzp[wave][lane] = nz;
    __syncthreads();

    float* __restrict__ rrow = red + (size_t)blk * RW;

    // wave 0: combine flags across waves, count + time-sum, shuffle-reduce
    if (wave == 0) {
        const unsigned m = nzp[0][lane] | nzp[1][lane] | nzp[2][lane] | nzp[3][lane];
        float cnt = 0.f, tsum = 0.f;
#pragma unroll
        for (int j = 0; j < NJ; ++j) {
            const float4 tv = *(const float4*)(tarr + (size_t)b * TT + t0 + 256 * j + 4 * lane);
            const unsigned mj = (m >> (4 * j)) & 0xFu;
            if (mj & 1u) { cnt += 1.f; tsum += tv.x; }
            if (mj & 2u) { cnt += 1.f; tsum += tv.y; }
            if (mj & 4u) { cnt += 1.f; tsum += tv.z; }
            if (mj & 8u) { cnt += 1.f; tsum += tv.w; }
        }
        for (int off = 32; off; off >>= 1) {
            cnt  += __shfl_down(cnt,  off, 64);
            tsum += __shfl_down(tsum, off, 64);
        }
        if (lane == 0) { rrow[74] = cnt; rrow[75] = tsum; }
    }

    // per-sensor sums: wave shuffle reduction, one plain store per value
#pragma unroll
    for (int si = 0; si < NSW; ++si) {
        const int s = wave + 4 * si;
        if (s < SS) {
            float vx = ax[si], vm = am[si];
            for (int off = 32; off; off >>= 1) {
                vx += __shfl_down(vx, off, 64);
                vm += __shfl_down(vm, off, 64);
            }
            if (lane == 0) { rrow[s] = vx; rrow[SS + s] = vm; }
        }
    }
}

// ---------------------------------------------------------------------------
// Kernel 2: per-batch head, 320 threads per block, one block per b.
// Sums the NC chunk-partials, then:
// pooled = (sxt @ W_sensor + smask*(b_sensor+b_time) + stime*W_time) / denom
// comb   = relu([pooled, static@W_static+b_static] @ W_merge + b_merge)
// out    = comb @ W_cls + b_cls
// ---------------------------------------------------------------------------
__global__ __launch_bounds__(320) void head_kernel(
    const float* __restrict__ red,       // [B*NC, RW]
    const float* __restrict__ statics,   // [B,ST]
    const float* __restrict__ W_sensor,  // [74,256]
    const float* __restrict__ b_sensor,  // [256]
    const float* __restrict__ W_time,    // [1,256]
    const float* __restrict__ b_time,    // [256]
    const float* __restrict__ W_static,  // [8,8]
    const float* __restrict__ b_static,  // [8]
    const float* __restrict__ W_merge,   // [264,264]
    const float* __restrict__ b_merge,   // [264]
    const float* __restrict__ W_cls,     // [264,2]
    const float* __restrict__ b_cls,     // [2]
    float* __restrict__ out)             // [B,2]
{
    const int b   = blockIdx.x;
    const int tid = threadIdx.x;

    __shared__ float sred[RW];
    __shared__ float comb[MER];
    __shared__ float comb2[MER];
    __shared__ float rbuf[10];

    if (tid < RW) {
        const float* rb = red + (size_t)b * NC * RW + tid;
        sred[tid] = (rb[0] + rb[RW]) + (rb[2 * RW] + rb[3 * RW]);
    }
    __syncthreads();

    const float smask = sred[74];
    const float stime = sred[75];
    const float inv   = 1.0f / fmaxf(smask, 1e-9f);

    if (tid < DD) {
        // pooled: one output dim per thread, fully unrolled (74 loads in flight)
        const int d = tid;
        float a0 = smask * (b_sensor[d] + b_time[d]) + stime * W_time[d];
        float a1 = 0.f;
#pragma unroll
        for (int f = 0; f < FF; f += 2) {
            a0 += sred[f]     * W_sensor[f * DD + d];
            a1 += sred[f + 1] * W_sensor[(f + 1) * DD + d];
        }
        comb[d] = (a0 + a1) * inv;
    } else if (tid < DD + STT) {
        const int j = tid - DD;
        float acc = b_static[j];
#pragma unroll
        for (int i = 0; i < STT; ++i)
            acc += statics[b * STT + i] * W_static[i * STT + j];
        comb[DD + j] = acc;
    }
    __syncthreads();

    // merge layer: one output per thread, 8-way unrolled inner loop
    if (tid < MER) {
        const int j = tid;
        float a[8];
#pragma unroll
        for (int k = 0; k < 8; ++k) a[k] = 0.f;
        for (int i = 0; i < MER; i += 8) {   // 264 = 33 * 8
#pragma unroll
            for (int k = 0; k < 8; ++k)
                a[k] += comb[i + k] * W_merge[(i + k) * MER + j];
        }
        const float acc = b_merge[j] +
            ((a[0] + a[1]) + (a[2] + a[3])) + ((a[4] + a[5]) + (a[6] + a[7]));
        comb2[j] = fmaxf(acc, 0.f);
    }
    __syncthreads();

    // classifier: parallel over i, block reduction
    float c0 = 0.f, c1 = 0.f;
    if (tid < MER) {
        const float v = comb2[tid];
        c0 = v * W_cls[tid * CC];
        c1 = v * W_cls[tid * CC + 1];
    }
    for (int off = 32; off; off >>= 1) {
        c0 += __shfl_down(c0, off, 64);
        c1 += __shfl_down(c1, off, 64);
    }
    const int wv = tid >> 6, ln = tid & 63;
    if (ln == 0) { rbuf[wv] = c0; rbuf[5 + wv] = c1; }
    __syncthreads();
    if (tid == 0)
        out[b * CC + 0] = b_cls[0] + rbuf[0] + rbuf[1] + rbuf[2] + rbuf[3] + rbuf[4];
    if (tid == 1)
        out[b * CC + 1] = b_cls[1] + rbuf[5] + rbuf[6] + rbuf[7] + rbuf[8] + rbuf[9];
}

extern "C" void kernel_launch(void* const* d_in, const int* in_sizes, int n_in,
                              void* d_out, int out_size, void* d_ws, size_t ws_size,
                              hipStream_t stream) {
    const float* x        = (const float*)d_in[0];
    const float* statics  = (const float*)d_in[1];
    const float* tarr     = (const float*)d_in[2];
    const int*   smk      = (const int*)  d_in[3];
    const float* W_sensor = (const float*)d_in[4];
    const float* b_sensor = (const float*)d_in[5];
    const float* W_time   = (const float*)d_in[6];
    const float* b_time   = (const float*)d_in[7];
    const float* W_static = (const float*)d_in[8];
    const float* b_static = (const float*)d_in[9];
    const float* W_merge  = (const float*)d_in[10];
    const float* b_merge  = (const float*)d_in[11];
    const float* W_cls    = (const float*)d_in[12];
    const float* b_cls    = (const float*)d_in[13];
    float* out = (float*)d_out;
    float* red = (float*)d_ws;   // [B*NC, RW] floats — every slot overwritten
                                 // each call, so no zero-init needed

    reduce_kernel<<<BB * NC, 256, 0, stream>>>(x, smk, tarr, red);
    head_kernel<<<BB, 320, 0, stream>>>(red, statics, W_sensor, b_sensor,
                                        W_time, b_time, W_static, b_static,
                                        W_merge, b_merge, W_cls, b_cls, out);
}

// Round 4
// 141.974 us; speedup vs baseline: 1.2385x; 1.0216x over previous
//
#include <hip/hip_runtime.h>
#include <hip/hip_bf16.h>

// Problem constants
#define BB   128   // batch
#define SS   37    // sensors
#define TT   2048  // time steps
#define DD   256   // d_model
#define STT  8     // static features
#define CC   2     // classes
#define MER  264   // DD + STT
#define FF   74    // 2*SS features

#define NC    4            // t-chunks per batch row
#define CHUNK (TT / NC)    // 512 = 2 x (64 lanes x float4)
#define NJ    (CHUNK / 256)// t-iterations per block (2)
#define RW    76           // partial row: 74 feature sums + cnt + tsum
#define NSW   10           // sensors per wave (stride-4 interleave covers 37..40)

// ---------------------------------------------------------------------------
// Kernel 1: streaming reduction over T. Branch-free inner loop: every wave
// does exactly NSW sensor-loads per j (out-of-range s clamped to 36 and its
// contribution zeroed via cndmask), so all loads issue as one unbroken burst
// — no s_cbranch between loads, fine-grained vmcnt overlap.
// Block (b, chunk) writes its own partial row red[b*NC+chunk][RW]; no atomics,
// no zero-init.
//   row[s]    = sum_t x[b,s,t]       (mask*x == x since mask==0 => all 0)
//   row[37+s] = sum_t smk[b,s,t]
//   row[74]   = sum_t mask[b,t],  row[75] = sum_t mask[b,t]*time[b,t]
// ---------------------------------------------------------------------------
__global__ __launch_bounds__(256) void reduce_kernel(
    const float* __restrict__ x,      // [B,S,T]
    const int*   __restrict__ smk,    // [B,S,T]
    const float* __restrict__ tarr,   // [B,T]
    float* __restrict__ red)          // [B*NC, RW] partials
{
    const int blk   = blockIdx.x;      // 0 .. B*NC-1
    const int b     = blk >> 2;
    const int chunk = blk & 3;
    const int t0    = chunk * CHUNK;
    const int wave  = threadIdx.x >> 6;
    const int lane  = threadIdx.x & 63;

    float ax[NSW];     // per-sensor x sums over this lane's t's
    float am[NSW];     // per-sensor mask sums
    unsigned nz = 0;   // nonzero flags: bit (4j+k) = t-slot k of iteration j
#pragma unroll
    for (int i = 0; i < NSW; ++i) { ax[i] = 0.f; am[i] = 0.f; }

#pragma unroll
    for (int j = 0; j < NJ; ++j) {
        const int tb = t0 + 256 * j + 4 * lane;
#pragma unroll
        for (int si = 0; si < NSW; ++si) {
            const int s_raw = wave + 4 * si;
            const int s     = (s_raw < SS) ? s_raw : (SS - 1);  // clamp, no branch
            const size_t base = ((size_t)(b * SS + s)) * TT + tb;
            const float4 xv = *(const float4*)(x + base);
            const int4   mv = *(const int4*)(smk + base);
            const float sx = (xv.x + xv.y) + (xv.z + xv.w);
            const float sm = (float)((mv.x + mv.y) + (mv.z + mv.w));
            ax[si] += (s_raw < SS) ? sx : 0.f;   // cndmask-predicated
            am[si] += (s_raw < SS) ? sm : 0.f;
            // nz from clamped s=36 re-reads is idempotent (same flags, OR)
            unsigned f = (unsigned)((xv.x != 0.f) | (mv.x != 0))
                       | ((unsigned)((xv.y != 0.f) | (mv.y != 0)) << 1)
                       | ((unsigned)((xv.z != 0.f) | (mv.z != 0)) << 2)
                       | ((unsigned)((xv.w != 0.f) | (mv.w != 0)) << 3);
            nz |= f << (4 * j);
        }
    }

    __shared__ unsigned nzp[4][64];
    nzp[wave][lane] = nz;
    __syncthreads();

    float* __restrict__ rrow = red + (size_t)blk * RW;

    // wave 0: combine flags across waves, count + time-sum, shuffle-reduce
    if (wave == 0) {
        const unsigned m = nzp[0][lane] | nzp[1][lane] | nzp[2][lane] | nzp[3][lane];
        float cnt = 0.f, tsum = 0.f;
#pragma unroll
        for (int j = 0; j < NJ; ++j) {
            const float4 tv = *(const float4*)(tarr + (size_t)b * TT + t0 + 256 * j + 4 * lane);
            const unsigned mj = (m >> (4 * j)) & 0xFu;
            if (mj & 1u) { cnt += 1.f; tsum += tv.x; }
            if (mj & 2u) { cnt += 1.f; tsum += tv.y; }
            if (mj & 4u) { cnt += 1.f; tsum += tv.z; }
            if (mj & 8u) { cnt += 1.f; tsum += tv.w; }
        }
        for (int off = 32; off; off >>= 1) {
            cnt  += __shfl_down(cnt,  off, 64);
            tsum += __shfl_down(tsum, off, 64);
        }
        if (lane == 0) { rrow[74] = cnt; rrow[75] = tsum; }
    }

    // per-sensor sums: wave shuffle reduction, one plain store per value
#pragma unroll
    for (int si = 0; si < NSW; ++si) {
        const int s_raw = wave + 4 * si;
        float vx = ax[si], vm = am[si];
        for (int off = 32; off; off >>= 1) {
            vx += __shfl_down(vx, off, 64);
            vm += __shfl_down(vm, off, 64);
        }
        if (lane == 0 && s_raw < SS) { rrow[s_raw] = vx; rrow[SS + s_raw] = vm; }
    }
}

// ---------------------------------------------------------------------------
// Kernel 2: per-batch head, 320 threads per block, one block per b.
// Sums the NC chunk-partials, then:
// pooled = (sxt @ W_sensor + smask*(b_sensor+b_time) + stime*W_time) / denom
// comb   = relu([pooled, static@W_static+b_static] @ W_merge + b_merge)
// out    = comb @ W_cls + b_cls
// ---------------------------------------------------------------------------
__global__ __launch_bounds__(320) void head_kernel(
    const float* __restrict__ red,       // [B*NC, RW]
    const float* __restrict__ statics,   // [B,ST]
    const float* __restrict__ W_sensor,  // [74,256]
    const float* __restrict__ b_sensor,  // [256]
    const float* __restrict__ W_time,    // [1,256]
    const float* __restrict__ b_time,    // [256]
    const float* __restrict__ W_static,  // [8,8]
    const float* __restrict__ b_static,  // [8]
    const float* __restrict__ W_merge,   // [264,264]
    const float* __restrict__ b_merge,   // [264]
    const float* __restrict__ W_cls,     // [264,2]
    const float* __restrict__ b_cls,     // [2]
    float* __restrict__ out)             // [B,2]
{
    const int b   = blockIdx.x;
    const int tid = threadIdx.x;

    __shared__ float sred[RW];
    __shared__ float comb[MER];
    __shared__ float comb2[MER];
    __shared__ float rbuf[10];

    if (tid < RW) {
        const float* rb = red + (size_t)b * NC * RW + tid;
        sred[tid] = (rb[0] + rb[RW]) + (rb[2 * RW] + rb[3 * RW]);
    }
    __syncthreads();

    const float smask = sred[74];
    const float stime = sred[75];
    const float inv   = 1.0f / fmaxf(smask, 1e-9f);

    if (tid < DD) {
        // pooled: one output dim per thread, fully unrolled (74 loads in flight)
        const int d = tid;
        float a0 = smask * (b_sensor[d] + b_time[d]) + stime * W_time[d];
        float a1 = 0.f;
#pragma unroll
        for (int f = 0; f < FF; f += 2) {
            a0 += sred[f]     * W_sensor[f * DD + d];
            a1 += sred[f + 1] * W_sensor[(f + 1) * DD + d];
        }
        comb[d] = (a0 + a1) * inv;
    } else if (tid < DD + STT) {
        const int j = tid - DD;
        float acc = b_static[j];
#pragma unroll
        for (int i = 0; i < STT; ++i)
            acc += statics[b * STT + i] * W_static[i * STT + j];
        comb[DD + j] = acc;
    }
    __syncthreads();

    // merge layer: one output per thread, 8-way unrolled inner loop
    if (tid < MER) {
        const int j = tid;
        float a[8];
#pragma unroll
        for (int k = 0; k < 8; ++k) a[k] = 0.f;
        for (int i = 0; i < MER; i += 8) {   // 264 = 33 * 8
#pragma unroll
            for (int k = 0; k < 8; ++k)
                a[k] += comb[i + k] * W_merge[(i + k) * MER + j];
        }
        const float acc = b_merge[j] +
            ((a[0] + a[1]) + (a[2] + a[3])) + ((a[4] + a[5]) + (a[6] + a[7]));
        comb2[j] = fmaxf(acc, 0.f);
    }
    __syncthreads();

    // classifier: parallel over i, block reduction
    float c0 = 0.f, c1 = 0.f;
    if (tid < MER) {
        const float v = comb2[tid];
        c0 = v * W_cls[tid * CC];
        c1 = v * W_cls[tid * CC + 1];
    }
    for (int off = 32; off; off >>= 1) {
        c0 += __shfl_down(c0, off, 64);
        c1 += __shfl_down(c1, off, 64);
    }
    const int wv = tid >> 6, ln = tid & 63;
    if (ln == 0) { rbuf[wv] = c0; rbuf[5 + wv] = c1; }
    __syncthreads();
    if (tid == 0)
        out[b * CC + 0] = b_cls[0] + rbuf[0] + rbuf[1] + rbuf[2] + rbuf[3] + rbuf[4];
    if (tid == 1)
        out[b * CC + 1] = b_cls[1] + rbuf[5] + rbuf[6] + rbuf[7] + rbuf[8] + rbuf[9];
}

extern "C" void kernel_launch(void* const* d_in, const int* in_sizes, int n_in,
                              void* d_out, int out_size, void* d_ws, size_t ws_size,
                              hipStream_t stream) {
    const float* x        = (const float*)d_in[0];
    const float* statics  = (const float*)d_in[1];
    const float* tarr     = (const float*)d_in[2];
    const int*   smk      = (const int*)  d_in[3];
    const float* W_sensor = (const float*)d_in[4];
    const float* b_sensor = (const float*)d_in[5];
    const float* W_time   = (const float*)d_in[6];
    const float* b_time   = (const float*)d_in[7];
    const float* W_static = (const float*)d_in[8];
    const float* b_static = (const float*)d_in[9];
    const float* W_merge  = (const float*)d_in[10];
    const float* b_merge  = (const float*)d_in[11];
    const float* W_cls    = (const float*)d_in[12];
    const float* b_cls    = (const float*)d_in[13];
    float* out = (float*)d_out;
    float* red = (float*)d_ws;   // [B*NC, RW] floats — every slot overwritten
                                 // each call, so no zero-init needed

    reduce_kernel<<<BB * NC, 256, 0, stream>>>(x, smk, tarr, red);
    head_kernel<<<BB, 320, 0, stream>>>(red, statics, W_sensor, b_sensor,
                                        W_time, b_time, W_static, b_static,
                                        W_merge, b_merge, W_cls, b_cls, out);
}